// Round 8
// baseline (248.023 us; speedup 1.0000x reference)
//
#include <hip/hip_runtime.h>
#include <cstdint>
#include <cstddef>

#define NEG_SLOPE 0.2f

typedef __bf16 bf16x8 __attribute__((ext_vector_type(8)));
typedef float f32x4 __attribute__((ext_vector_type(4)));

static __device__ __forceinline__ unsigned short f2bf(float f) {
  unsigned int u = __float_as_uint(f);
  unsigned int r = (u + 0x7FFFu + ((u >> 16) & 1u)) >> 16;
  return (unsigned short)r;
}
static __device__ __forceinline__ float bf2f(unsigned short u) {
  return __uint_as_float(((unsigned int)u) << 16);
}
static __device__ __forceinline__ float pklo(unsigned int x) {
  return __uint_as_float(x << 16);
}
static __device__ __forceinline__ float pkhi(unsigned int x) {
  return __uint_as_float(x & 0xffff0000u);
}

// ---------------- CSR build ----------------
__global__ void k_zero_i32(int* __restrict__ p, int n) {
  int i = blockIdx.x * 256 + threadIdx.x;
  if (i < n) p[i] = 0;
}

__global__ void k_degree(const int* __restrict__ ei, int* __restrict__ deg, int E) {
  int e = blockIdx.x * 256 + threadIdx.x;
  if (e < E) atomicAdd(&deg[ei[E + e]], 1);  // ei[E+e] = dst
}

__global__ __launch_bounds__(256) void k_scan_local(const int* __restrict__ deg,
                                                    int* __restrict__ lex,
                                                    int* __restrict__ bsum, int n) {
  __shared__ int ts[256];
  const int t = threadIdx.x;
  const int base = blockIdx.x * 1024 + t * 4;
  int4 d = {0, 0, 0, 0};
  if (base + 3 < n) d = *reinterpret_cast<const int4*>(&deg[base]);
  else {
    if (base + 0 < n) d.x = deg[base + 0];
    if (base + 1 < n) d.y = deg[base + 1];
    if (base + 2 < n) d.z = deg[base + 2];
  }
  int s = d.x + d.y + d.z + d.w;
  ts[t] = s;
  __syncthreads();
  for (int off = 1; off < 256; off <<= 1) {
    int y = (t >= off) ? ts[t - off] : 0;
    __syncthreads();
    ts[t] += y;
    __syncthreads();
  }
  int pre = ts[t] - s;
  int4 o;
  o.x = pre; o.y = pre + d.x; o.z = pre + d.x + d.y; o.w = pre + d.x + d.y + d.z;
  if (base + 3 < n) *reinterpret_cast<int4*>(&lex[base]) = o;
  else {
    if (base + 0 < n) lex[base + 0] = o.x;
    if (base + 1 < n) lex[base + 1] = o.y;
    if (base + 2 < n) lex[base + 2] = o.z;
  }
  if (t == 255) bsum[blockIdx.x] = ts[255];
}

__global__ __launch_bounds__(256) void k_scan_bsum(int* __restrict__ bsum, int nb) {
  __shared__ int ts[256];
  const int t = threadIdx.x;
  int v = (t < nb) ? bsum[t] : 0;
  ts[t] = v;
  __syncthreads();
  for (int off = 1; off < 256; off <<= 1) {
    int y = (t >= off) ? ts[t - off] : 0;
    __syncthreads();
    ts[t] += y;
    __syncthreads();
  }
  if (t < nb) bsum[t] = ts[t] - v;
}

__global__ void k_scan_add(const int* __restrict__ lex, const int* __restrict__ bsum,
                           int* __restrict__ rowptr, int* __restrict__ cursor,
                           int n, int E) {
  int i = blockIdx.x * 256 + threadIdx.x;
  if (i < n) {
    int v = lex[i] + bsum[i >> 10];
    rowptr[i] = v;
    cursor[i] = v;
  }
  if (i == n) rowptr[n] = E;
}

__global__ void k_scatter(const int* __restrict__ ei, int* __restrict__ cursor,
                          int* __restrict__ col, int E) {
  int e = blockIdx.x * 256 + threadIdx.x;
  if (e >= E) return;
  int d = ei[E + e];
  int pos = atomicAdd(&cursor[d], 1);
  col[pos] = ei[e];
}

// ---------------- weight prep (all layers in one launch) ----------------
static __device__ __forceinline__ unsigned short pack_wt_elem(
    const float* __restrict__ Wl, const float* __restrict__ Ws,
    const float* __restrict__ Wd, const float* __restrict__ as_,
    const float* __restrict__ ad_, int t) {
  int j = t >> 7, k = t & 127;
  float val;
  if (j < 128) val = Wl[k * 128 + j];
  else if (j < 256) val = Ws[k * 128 + (j - 128)];
  else {
    int jj = j - 256;
    int h = jj & 7;
    const float* W = (jj < 8) ? Ws : Wd;
    const float* a = (jj < 8) ? as_ : ad_;
    float s = 0.f;
#pragma unroll
    for (int c = 0; c < 16; ++c) s += W[k * 128 + h * 16 + c] * a[h * 16 + c];
    val = s;
  }
  return f2bf(val);
}

__global__ void k_pack_all(
    const float* __restrict__ Wl0, const float* __restrict__ Ws0, const float* __restrict__ Wd0,
    const float* __restrict__ as0, const float* __restrict__ ad0,
    const float* __restrict__ Wl1, const float* __restrict__ Ws1, const float* __restrict__ Wd1,
    const float* __restrict__ as1, const float* __restrict__ ad1,
    const float* __restrict__ Wo,
    unsigned short* __restrict__ wt0, unsigned short* __restrict__ wt1,
    unsigned short* __restrict__ wot) {
  const int SZ = 272 * 128;
  int t = blockIdx.x * 256 + threadIdx.x;
  if (t < SZ) {
    wt0[t] = pack_wt_elem(Wl0, Ws0, Wd0, as0, ad0, t);
  } else if (t < 2 * SZ) {
    wt1[t - SZ] = pack_wt_elem(Wl1, Ws1, Wd1, as1, ad1, t - SZ);
  } else if (t < 2 * SZ + 64 * 128) {
    int u = t - 2 * SZ;
    int nn = u >> 7, k = u & 127;
    wot[u] = f2bf(Wo[k * 64 + nn]);
  }
}

// ---------------- persistent fused MFMA GEMM ----------------
// Outputs: ylin[N][128] f32 (+b_lin+b_conv folded), xsb[N][128] bf16,
// asd_s[N][8] bf16, asd_d[N][8] bf16 (all natural row-major). 8 waves.
template <typename TIN>
__global__ __launch_bounds__(512) void k_gemm_fused(
    const TIN* __restrict__ X, const unsigned short* __restrict__ wt,
    const float* __restrict__ bl, const float* __restrict__ bc,
    float* __restrict__ ylin, unsigned short* __restrict__ xsb,
    unsigned short* __restrict__ asd_s, unsigned short* __restrict__ asd_d,
    int n, int ntiles) {
  __shared__ __align__(16) unsigned short ws[272][136];
  __shared__ __align__(16) unsigned short xa[2][64][136];
  const int tid = threadIdx.x;

  for (int i = tid; i < 4352; i += 512) {   // stage ws once
    int r = i >> 4, ko = i & 15;
    *reinterpret_cast<uint4*>(&ws[r][ko * 8]) =
        reinterpret_cast<const uint4*>(wt)[(size_t)r * 16 + ko];
  }

  const int wave = tid >> 6, lane = tid & 63;
  const int gh = wave >> 2, fs = wave & 3;
  const int lr = lane & 15, lg = lane >> 4;
  const int f0 = fs * 4;
  const int nf = (fs == 3) ? 5 : 4;   // fs==3 also owns f=16 (asd)

  float4 rf[4];
  uint4 ru[2];
  int t = blockIdx.x;

#define LOAD_T(tt)                                                              \
  do {                                                                          \
    int row0_ = (tt) * 64;                                                      \
    if constexpr (sizeof(TIN) == 4) {                                           \
      _Pragma("unroll") for (int i = 0; i < 4; ++i) {                           \
        int c = tid + i * 512; int r = c >> 5, kq = c & 31;                     \
        rf[i] = make_float4(0.f, 0.f, 0.f, 0.f);                                \
        if (row0_ + r < n)                                                      \
          rf[i] = reinterpret_cast<const float4*>(X)[(size_t)(row0_ + r) * 32 + kq]; \
      }                                                                         \
    } else {                                                                    \
      _Pragma("unroll") for (int i = 0; i < 2; ++i) {                           \
        int c = tid + i * 512; int r = c >> 4, ko = c & 15;                     \
        ru[i] = uint4{0u, 0u, 0u, 0u};                                          \
        if (row0_ + r < n)                                                      \
          ru[i] = reinterpret_cast<const uint4*>(X)[(size_t)(row0_ + r) * 16 + ko]; \
      }                                                                         \
    }                                                                           \
  } while (0)

  LOAD_T(t);
  int buf = 0;
  for (; t < ntiles; t += gridDim.x) {
    if constexpr (sizeof(TIN) == 4) {
#pragma unroll
      for (int i = 0; i < 4; ++i) {
        int c = tid + i * 512; int r = c >> 5, kq = c & 31;
        ushort4 o;
        o.x = f2bf(rf[i].x); o.y = f2bf(rf[i].y); o.z = f2bf(rf[i].z); o.w = f2bf(rf[i].w);
        *reinterpret_cast<ushort4*>(&xa[buf][r][kq * 4]) = o;
      }
    } else {
#pragma unroll
      for (int i = 0; i < 2; ++i) {
        int c = tid + i * 512; int r = c >> 4, ko = c & 15;
        *reinterpret_cast<uint4*>(&xa[buf][r][ko * 8]) = ru[i];
      }
    }
    int tn = t + gridDim.x;
    if (tn < ntiles) LOAD_T(tn);   // issue next-tile loads early
    __syncthreads();

    const int row0 = t * 64;
    f32x4 acc[2][5];
#pragma unroll
    for (int g2 = 0; g2 < 2; ++g2)
#pragma unroll
      for (int ff = 0; ff < 5; ++ff) acc[g2][ff] = (f32x4){0.f, 0.f, 0.f, 0.f};

#pragma unroll
    for (int s = 0; s < 4; ++s) {
      bf16x8 a0 = *reinterpret_cast<const bf16x8*>(&xa[buf][gh * 32 + lr][s * 32 + lg * 8]);
      bf16x8 a1 = *reinterpret_cast<const bf16x8*>(&xa[buf][gh * 32 + 16 + lr][s * 32 + lg * 8]);
#pragma unroll
      for (int ff = 0; ff < 5; ++ff) {
        if (ff < nf) {
          int f = f0 + ff;
          bf16x8 b = *reinterpret_cast<const bf16x8*>(&ws[f * 16 + lr][s * 32 + lg * 8]);
          acc[0][ff] = __builtin_amdgcn_mfma_f32_16x16x32_bf16(a0, b, acc[0][ff], 0, 0, 0);
          acc[1][ff] = __builtin_amdgcn_mfma_f32_16x16x32_bf16(a1, b, acc[1][ff], 0, 0, 0);
        }
      }
    }

#pragma unroll
    for (int g2 = 0; g2 < 2; ++g2) {
      const int g = gh * 2 + g2;
#pragma unroll
      for (int ff = 0; ff < 5; ++ff) {
        if (ff < nf) {
          const int f = f0 + ff;
#pragma unroll
          for (int r = 0; r < 4; ++r) {
            int row = row0 + g * 16 + lg * 4 + r;
            if (row < n) {
              float v = acc[g2][ff][r];
              if (f < 8) {
                int j = f * 16 + lr;
                ylin[(size_t)row * 128 + j] = v + bl[j] + bc[j];
              } else if (f < 16) {
                xsb[(size_t)row * 128 + (f - 8) * 16 + lr] = f2bf(v);
              } else {
                if (lr < 8) asd_s[(size_t)row * 8 + lr] = f2bf(v);
                else        asd_d[(size_t)row * 8 + (lr - 8)] = f2bf(v);
              }
            }
          }
        }
      }
    }
    __syncthreads();
    buf ^= 1;
  }
#undef LOAD_T
}

// ---------------- final MFMA GEMM: out[N,64] = h@W_out + b (h bf16) ----------------
__global__ __launch_bounds__(256) void k_gemm_out(
    const unsigned short* __restrict__ X, const unsigned short* __restrict__ wo,
    const float* __restrict__ bias, float* __restrict__ out, int n) {
  __shared__ __align__(16) unsigned short xa[64][136];
  __shared__ __align__(16) unsigned short ws[64][136];
  const int tid = threadIdx.x;
  const int row0 = blockIdx.x * 64;

#pragma unroll
  for (int i = 0; i < 4; ++i) {
    int c = tid + i * 256;
    int r = c >> 4, ko = c & 15;
    uint4 v = {0u, 0u, 0u, 0u};
    if (row0 + r < n)
      v = reinterpret_cast<const uint4*>(X)[(size_t)(row0 + r) * 16 + ko];
    *reinterpret_cast<uint4*>(&xa[r][ko * 8]) = v;
  }
#pragma unroll
  for (int i = 0; i < 4; ++i) {
    int c = tid + i * 256;
    int r = c >> 4, ko = c & 15;
    *reinterpret_cast<uint4*>(&ws[r][ko * 8]) =
        reinterpret_cast<const uint4*>(wo)[(size_t)r * 16 + ko];
  }
  __syncthreads();

  const int w = tid >> 6, lane = tid & 63;
  const int lr = lane & 15, lg = lane >> 4;
  f32x4 acc[4];
#pragma unroll
  for (int f = 0; f < 4; ++f) acc[f] = (f32x4){0.f, 0.f, 0.f, 0.f};

#pragma unroll
  for (int s = 0; s < 4; ++s) {
    bf16x8 a = *reinterpret_cast<const bf16x8*>(&xa[w * 16 + lr][s * 32 + lg * 8]);
#pragma unroll
    for (int f = 0; f < 4; ++f) {
      bf16x8 b = *reinterpret_cast<const bf16x8*>(&ws[f * 16 + lr][s * 32 + lg * 8]);
      acc[f] = __builtin_amdgcn_mfma_f32_16x16x32_bf16(a, b, acc[f], 0, 0, 0);
    }
  }
#pragma unroll
  for (int f = 0; f < 4; ++f) {
#pragma unroll
    for (int r = 0; r < 4; ++r) {
      int row = row0 + w * 16 + lg * 4 + r;
      if (row < n)
        out[(size_t)row * 64 + f * 16 + lr] = acc[f][r] + bias[f * 16 + lr];
    }
  }
}

// ---------------- fused segment softmax + aggregation + node update ----------------
// One wave per dst node. Per 8-edge chunk:
//   phase1: lane = (edge-slot el=lane>>3, head hh=lane&7) computes
//           p = exp(leaky(asd_s[col[e]][hh] + asd_d[node][hh])) — 8 exps/edge.
//   phase2: lane owns channels (2*lane, 2*lane+1), head h=lane>>3; gets p via
//           ds_bpermute(lane <- el*8+h) and src via readlane. Wave-sync, no barrier.
__global__ __launch_bounds__(256) void k_aggregate(
    const float* __restrict__ ylin, const unsigned int* __restrict__ xsp,
    const unsigned short* __restrict__ asd_s, const unsigned short* __restrict__ asd_d,
    const int* __restrict__ rowptr, const int* __restrict__ col,
    unsigned int* __restrict__ hout_pk, int n) {
  int node = (blockIdx.x * blockDim.x + threadIdx.x) >> 6;
  if (node >= n) return;
  const int lane = threadIdx.x & 63;
  const int el = lane >> 3;             // phase1 edge slot
  const int hh = lane & 7;              // phase1 head
  const int hb4 = (lane >> 3) << 2;     // phase2: h*4 bpermute byte base (h = lane>>3)
  const int beg = rowptr[node], end = rowptr[node + 1];

  const float ad_hh = bf2f(asd_d[(size_t)node * 8 + hh]);

  float dsum = 0.f, acc0 = 0.f, acc1 = 0.f;
  for (int ebase = beg; ebase < end; ebase += 8) {
    int e1 = ebase + el;
    int esafe = (e1 < end) ? e1 : (end - 1);
    int srcp = col[esafe];
    float sv = bf2f(asd_s[(size_t)srcp * 8 + hh]) + ad_hh;
    sv = fmaxf(sv, NEG_SLOPE * sv);
    float pe = (e1 < end) ? __expf(sv) : 0.f;
#pragma unroll
    for (int q = 0; q < 8; ++q) {
      if (ebase + q >= end) break;      // wave-uniform
      float pq = __uint_as_float(__builtin_amdgcn_ds_bpermute(
          q * 32 + hb4, __float_as_uint(pe)));
      int sq = __builtin_amdgcn_readlane(srcp, q * 8);
      unsigned int xv = xsp[(size_t)sq * 64 + lane];
      dsum += pq;
      acc0 += pq * pklo(xv);
      acc1 += pq * pkhi(xv);
    }
  }
  float inv = 1.f / (dsum + 1e-16f);
  float2 y = reinterpret_cast<const float2*>(ylin)[(size_t)node * 64 + lane];
  float l0 = y.x + acc0 * inv;
  float l1 = y.y + acc1 * inv;
  l0 = l0 > 0.f ? l0 : __expf(l0) - 1.f;
  l1 = l1 > 0.f ? l1 : __expf(l1) - 1.f;
  hout_pk[(size_t)node * 64 + lane] =
      (unsigned int)f2bf(l0) | ((unsigned int)f2bf(l1) << 16);
}

// ---------------- launch ----------------
extern "C" void kernel_launch(void* const* d_in, const int* in_sizes, int n_in,
                              void* d_out, int out_size, void* d_ws, size_t ws_size,
                              hipStream_t stream) {
  const float* x      = (const float*)d_in[0];
  const int*   ei     = (const int*)d_in[1];
  const float* W_lin0 = (const float*)d_in[2];
  const float* b_lin0 = (const float*)d_in[3];
  const float* W_src0 = (const float*)d_in[4];
  const float* W_dst0 = (const float*)d_in[5];
  const float* att_s0 = (const float*)d_in[6];
  const float* att_d0 = (const float*)d_in[7];
  const float* b_cnv0 = (const float*)d_in[8];
  const float* W_lin1 = (const float*)d_in[9];
  const float* b_lin1 = (const float*)d_in[10];
  const float* W_src1 = (const float*)d_in[11];
  const float* W_dst1 = (const float*)d_in[12];
  const float* att_s1 = (const float*)d_in[13];
  const float* att_d1 = (const float*)d_in[14];
  const float* b_cnv1 = (const float*)d_in[15];
  const float* W_out  = (const float*)d_in[16];
  const float* b_out  = (const float*)d_in[17];
  float* out = (float*)d_out;

  const int N = in_sizes[0] / 128;
  const int E = in_sizes[1] / 2;
  const int NB = (N + 1023) / 1024;
  const int NTILES = (N + 63) / 64;

  char* p = (char*)d_ws;
  float* ylin           = (float*)p;          p += (size_t)N * 128 * 4;
  unsigned short* xsb   = (unsigned short*)p; p += (size_t)N * 128 * 2;
  unsigned short* hb    = (unsigned short*)p; p += (size_t)N * 128 * 2;
  unsigned short* asd_s = (unsigned short*)p; p += (size_t)N * 8 * 2;
  unsigned short* asd_d = (unsigned short*)p; p += (size_t)N * 8 * 2;
  unsigned short* wt0   = (unsigned short*)p; p += (size_t)272 * 128 * 2;
  unsigned short* wt1   = (unsigned short*)p; p += (size_t)272 * 128 * 2;
  unsigned short* wot   = (unsigned short*)p; p += (size_t)64 * 128 * 2;
  int* rowptr = (int*)p;                      p += (size_t)(N + 4) * 4;
  int* cursor = (int*)p;                      p += (size_t)N * 4;
  int* deg    = (int*)p;                      p += (size_t)N * 4;
  int* lex    = (int*)p;                      p += (size_t)N * 4;
  int* bsum   = (int*)p;                      p += (size_t)256 * 4;
  int* col    = (int*)p;                      p += (size_t)E * 4;

  dim3 b256(256);

  // CSR by dst (shared by both layers)
  k_zero_i32<<<(N + 255) / 256, b256, 0, stream>>>(deg, N);
  k_degree<<<(E + 255) / 256, b256, 0, stream>>>(ei, deg, E);
  k_scan_local<<<NB, b256, 0, stream>>>(deg, lex, bsum, N);
  k_scan_bsum<<<1, b256, 0, stream>>>(bsum, NB);
  k_scan_add<<<(N + 256) / 256, b256, 0, stream>>>(lex, bsum, rowptr, cursor, N, E);
  k_scatter<<<(E + 255) / 256, b256, 0, stream>>>(ei, cursor, col, E);

  // all weight packs in one launch
  k_pack_all<<<(2 * 272 * 128 + 64 * 128 + 255) / 256, b256, 0, stream>>>(
      W_lin0, W_src0, W_dst0, att_s0, att_d0,
      W_lin1, W_src1, W_dst1, att_s1, att_d1,
      W_out, wt0, wt1, wot);

  for (int layer = 0; layer < 2; ++layer) {
    const float* bl = layer ? b_lin1 : b_lin0;
    const float* bc = layer ? b_cnv1 : b_cnv0;
    const unsigned short* wt = layer ? wt1 : wt0;

    if (layer == 0)
      k_gemm_fused<float><<<256, 512, 0, stream>>>(x, wt, bl, bc, ylin, xsb,
                                                   asd_s, asd_d, N, NTILES);
    else
      k_gemm_fused<unsigned short><<<256, 512, 0, stream>>>(hb, wt, bl, bc, ylin, xsb,
                                                            asd_s, asd_d, N, NTILES);
    k_aggregate<<<(N + 3) / 4, b256, 0, stream>>>(
        ylin, (const unsigned int*)xsb, asd_s, asd_d, rowptr, col,
        (unsigned int*)hb, N);
  }
  k_gemm_out<<<(N + 63) / 64, b256, 0, stream>>>(hb, wot, b_out, out, N);
}

// Round 9
// 222.653 us; speedup vs baseline: 1.1139x; 1.1139x over previous
//
#include <hip/hip_runtime.h>
#include <cstdint>
#include <cstddef>

#define NEG_SLOPE 0.2f

typedef __bf16 bf16x8 __attribute__((ext_vector_type(8)));
typedef float f32x4 __attribute__((ext_vector_type(4)));

static __device__ __forceinline__ unsigned short f2bf(float f) {
  unsigned int u = __float_as_uint(f);
  unsigned int r = (u + 0x7FFFu + ((u >> 16) & 1u)) >> 16;
  return (unsigned short)r;
}
static __device__ __forceinline__ float bf2f(unsigned short u) {
  return __uint_as_float(((unsigned int)u) << 16);
}
static __device__ __forceinline__ float pklo(unsigned int x) {
  return __uint_as_float(x << 16);
}
static __device__ __forceinline__ float pkhi(unsigned int x) {
  return __uint_as_float(x & 0xffff0000u);
}

// ---------------- CSR build ----------------
__global__ void k_zero_i32(int* __restrict__ p, int n) {
  int i = blockIdx.x * 256 + threadIdx.x;
  if (i < n) p[i] = 0;
}

__global__ void k_degree(const int* __restrict__ ei, int* __restrict__ deg, int E) {
  int e = blockIdx.x * 256 + threadIdx.x;
  if (e < E) atomicAdd(&deg[ei[E + e]], 1);  // ei[E+e] = dst
}

__global__ __launch_bounds__(256) void k_scan_local(const int* __restrict__ deg,
                                                    int* __restrict__ lex,
                                                    int* __restrict__ bsum, int n) {
  __shared__ int ts[256];
  const int t = threadIdx.x;
  const int base = blockIdx.x * 1024 + t * 4;
  int4 d = {0, 0, 0, 0};
  if (base + 3 < n) d = *reinterpret_cast<const int4*>(&deg[base]);
  else {
    if (base + 0 < n) d.x = deg[base + 0];
    if (base + 1 < n) d.y = deg[base + 1];
    if (base + 2 < n) d.z = deg[base + 2];
  }
  int s = d.x + d.y + d.z + d.w;
  ts[t] = s;
  __syncthreads();
  for (int off = 1; off < 256; off <<= 1) {
    int y = (t >= off) ? ts[t - off] : 0;
    __syncthreads();
    ts[t] += y;
    __syncthreads();
  }
  int pre = ts[t] - s;
  int4 o;
  o.x = pre; o.y = pre + d.x; o.z = pre + d.x + d.y; o.w = pre + d.x + d.y + d.z;
  if (base + 3 < n) *reinterpret_cast<int4*>(&lex[base]) = o;
  else {
    if (base + 0 < n) lex[base + 0] = o.x;
    if (base + 1 < n) lex[base + 1] = o.y;
    if (base + 2 < n) lex[base + 2] = o.z;
  }
  if (t == 255) bsum[blockIdx.x] = ts[255];
}

__global__ __launch_bounds__(256) void k_scan_bsum(int* __restrict__ bsum, int nb) {
  __shared__ int ts[256];
  const int t = threadIdx.x;
  int v = (t < nb) ? bsum[t] : 0;
  ts[t] = v;
  __syncthreads();
  for (int off = 1; off < 256; off <<= 1) {
    int y = (t >= off) ? ts[t - off] : 0;
    __syncthreads();
    ts[t] += y;
    __syncthreads();
  }
  if (t < nb) bsum[t] = ts[t] - v;
}

__global__ void k_scan_add(const int* __restrict__ lex, const int* __restrict__ bsum,
                           int* __restrict__ rowptr, int* __restrict__ cursor,
                           int n, int E) {
  int i = blockIdx.x * 256 + threadIdx.x;
  if (i < n) {
    int v = lex[i] + bsum[i >> 10];
    rowptr[i] = v;
    cursor[i] = v;
  }
  if (i == n) rowptr[n] = E;
}

__global__ void k_scatter(const int* __restrict__ ei, int* __restrict__ cursor,
                          int* __restrict__ col, int E) {
  int e = blockIdx.x * 256 + threadIdx.x;
  if (e >= E) return;
  int d = ei[E + e];
  int pos = atomicAdd(&cursor[d], 1);
  col[pos] = ei[e];
}

// ---------------- weight prep (all layers in one launch) ----------------
static __device__ __forceinline__ unsigned short pack_wt_elem(
    const float* __restrict__ Wl, const float* __restrict__ Ws,
    const float* __restrict__ Wd, const float* __restrict__ as_,
    const float* __restrict__ ad_, int t) {
  int j = t >> 7, k = t & 127;
  float val;
  if (j < 128) val = Wl[k * 128 + j];
  else if (j < 256) val = Ws[k * 128 + (j - 128)];
  else {
    int jj = j - 256;
    int h = jj & 7;
    const float* W = (jj < 8) ? Ws : Wd;
    const float* a = (jj < 8) ? as_ : ad_;
    float s = 0.f;
#pragma unroll
    for (int c = 0; c < 16; ++c) s += W[k * 128 + h * 16 + c] * a[h * 16 + c];
    val = s;
  }
  return f2bf(val);
}

__global__ void k_pack_all(
    const float* __restrict__ Wl0, const float* __restrict__ Ws0, const float* __restrict__ Wd0,
    const float* __restrict__ as0, const float* __restrict__ ad0,
    const float* __restrict__ Wl1, const float* __restrict__ Ws1, const float* __restrict__ Wd1,
    const float* __restrict__ as1, const float* __restrict__ ad1,
    const float* __restrict__ Wo,
    unsigned short* __restrict__ wt0, unsigned short* __restrict__ wt1,
    unsigned short* __restrict__ wot) {
  const int SZ = 272 * 128;
  int t = blockIdx.x * 256 + threadIdx.x;
  if (t < SZ) {
    wt0[t] = pack_wt_elem(Wl0, Ws0, Wd0, as0, ad0, t);
  } else if (t < 2 * SZ) {
    wt1[t - SZ] = pack_wt_elem(Wl1, Ws1, Wd1, as1, ad1, t - SZ);
  } else if (t < 2 * SZ + 64 * 128) {
    int u = t - 2 * SZ;
    int nn = u >> 7, k = u & 127;
    wot[u] = f2bf(Wo[k * 64 + nn]);
  }
}

// ---------------- persistent fused MFMA GEMM ----------------
// Outputs: ylin_pk[N][64] uint (bf16 channel pairs, +b_lin+b_conv folded),
// xsb[N][128] bf16, asd_s[N][8] bf16, asd_d[N][8] bf16. 8 waves.
template <typename TIN>
__global__ __launch_bounds__(512) void k_gemm_fused(
    const TIN* __restrict__ X, const unsigned short* __restrict__ wt,
    const float* __restrict__ bl, const float* __restrict__ bc,
    unsigned int* __restrict__ ylin_pk, unsigned short* __restrict__ xsb,
    unsigned short* __restrict__ asd_s, unsigned short* __restrict__ asd_d,
    int n, int ntiles) {
  __shared__ __align__(16) unsigned short ws[272][136];
  __shared__ __align__(16) unsigned short xa[2][64][136];
  const int tid = threadIdx.x;

  for (int i = tid; i < 4352; i += 512) {   // stage ws once
    int r = i >> 4, ko = i & 15;
    *reinterpret_cast<uint4*>(&ws[r][ko * 8]) =
        reinterpret_cast<const uint4*>(wt)[(size_t)r * 16 + ko];
  }

  const int wave = tid >> 6, lane = tid & 63;
  const int gh = wave >> 2, fs = wave & 3;
  const int lr = lane & 15, lg = lane >> 4;
  const int f0 = fs * 4;
  const int nf = (fs == 3) ? 5 : 4;   // fs==3 also owns f=16 (asd)

  float4 rf[4];
  uint4 ru[2];
  int t = blockIdx.x;

#define LOAD_T(tt)                                                              \
  do {                                                                          \
    int row0_ = (tt) * 64;                                                      \
    if constexpr (sizeof(TIN) == 4) {                                           \
      _Pragma("unroll") for (int i = 0; i < 4; ++i) {                           \
        int c = tid + i * 512; int r = c >> 5, kq = c & 31;                     \
        rf[i] = make_float4(0.f, 0.f, 0.f, 0.f);                                \
        if (row0_ + r < n)                                                      \
          rf[i] = reinterpret_cast<const float4*>(X)[(size_t)(row0_ + r) * 32 + kq]; \
      }                                                                         \
    } else {                                                                    \
      _Pragma("unroll") for (int i = 0; i < 2; ++i) {                           \
        int c = tid + i * 512; int r = c >> 4, ko = c & 15;                     \
        ru[i] = uint4{0u, 0u, 0u, 0u};                                          \
        if (row0_ + r < n)                                                      \
          ru[i] = reinterpret_cast<const uint4*>(X)[(size_t)(row0_ + r) * 16 + ko]; \
      }                                                                         \
    }                                                                           \
  } while (0)

  LOAD_T(t);
  int buf = 0;
  for (; t < ntiles; t += gridDim.x) {
    if constexpr (sizeof(TIN) == 4) {
#pragma unroll
      for (int i = 0; i < 4; ++i) {
        int c = tid + i * 512; int r = c >> 5, kq = c & 31;
        ushort4 o;
        o.x = f2bf(rf[i].x); o.y = f2bf(rf[i].y); o.z = f2bf(rf[i].z); o.w = f2bf(rf[i].w);
        *reinterpret_cast<ushort4*>(&xa[buf][r][kq * 4]) = o;
      }
    } else {
#pragma unroll
      for (int i = 0; i < 2; ++i) {
        int c = tid + i * 512; int r = c >> 4, ko = c & 15;
        *reinterpret_cast<uint4*>(&xa[buf][r][ko * 8]) = ru[i];
      }
    }
    int tn = t + gridDim.x;
    if (tn < ntiles) LOAD_T(tn);   // issue next-tile loads early
    __syncthreads();

    const int row0 = t * 64;
    f32x4 acc[2][5];
#pragma unroll
    for (int g2 = 0; g2 < 2; ++g2)
#pragma unroll
      for (int ff = 0; ff < 5; ++ff) acc[g2][ff] = (f32x4){0.f, 0.f, 0.f, 0.f};

#pragma unroll
    for (int s = 0; s < 4; ++s) {
      bf16x8 a0 = *reinterpret_cast<const bf16x8*>(&xa[buf][gh * 32 + lr][s * 32 + lg * 8]);
      bf16x8 a1 = *reinterpret_cast<const bf16x8*>(&xa[buf][gh * 32 + 16 + lr][s * 32 + lg * 8]);
#pragma unroll
      for (int ff = 0; ff < 5; ++ff) {
        if (ff < nf) {
          int f = f0 + ff;
          bf16x8 b = *reinterpret_cast<const bf16x8*>(&ws[f * 16 + lr][s * 32 + lg * 8]);
          acc[0][ff] = __builtin_amdgcn_mfma_f32_16x16x32_bf16(a0, b, acc[0][ff], 0, 0, 0);
          acc[1][ff] = __builtin_amdgcn_mfma_f32_16x16x32_bf16(a1, b, acc[1][ff], 0, 0, 0);
        }
      }
    }

#pragma unroll
    for (int g2 = 0; g2 < 2; ++g2) {
      const int g = gh * 2 + g2;
#pragma unroll
      for (int ff = 0; ff < 5; ++ff) {
        if (ff < nf) {
          const int f = f0 + ff;
#pragma unroll
          for (int r = 0; r < 4; ++r) {
            int row = row0 + g * 16 + lg * 4 + r;
            float v = acc[g2][ff][r];
            if (f < 8) {
              // pack channel pair (j even, j odd) into one uint; partner via shfl
              int j = f * 16 + lr;
              float vb = v + bl[j] + bc[j];
              float v2 = __shfl(vb, lane ^ 1);   // pair-uniform branch below
              if (row < n && (lr & 1) == 0) {
                unsigned int pk = (unsigned int)f2bf(vb) | ((unsigned int)f2bf(v2) << 16);
                ylin_pk[(size_t)row * 64 + (j >> 1)] = pk;
              }
            } else if (row < n) {
              if (f < 16) {
                xsb[(size_t)row * 128 + (f - 8) * 16 + lr] = f2bf(v);
              } else {
                if (lr < 8) asd_s[(size_t)row * 8 + lr] = f2bf(v);
                else        asd_d[(size_t)row * 8 + (lr - 8)] = f2bf(v);
              }
            }
          }
        }
      }
    }
    __syncthreads();
    buf ^= 1;
  }
#undef LOAD_T
}

// ---------------- final MFMA GEMM: out[N,64] = h@W_out + b (h bf16) ----------------
__global__ __launch_bounds__(256) void k_gemm_out(
    const unsigned short* __restrict__ X, const unsigned short* __restrict__ wo,
    const float* __restrict__ bias, float* __restrict__ out, int n) {
  __shared__ __align__(16) unsigned short xa[64][136];
  __shared__ __align__(16) unsigned short ws[64][136];
  const int tid = threadIdx.x;
  const int row0 = blockIdx.x * 64;

#pragma unroll
  for (int i = 0; i < 4; ++i) {
    int c = tid + i * 256;
    int r = c >> 4, ko = c & 15;
    uint4 v = {0u, 0u, 0u, 0u};
    if (row0 + r < n)
      v = reinterpret_cast<const uint4*>(X)[(size_t)(row0 + r) * 16 + ko];
    *reinterpret_cast<uint4*>(&xa[r][ko * 8]) = v;
  }
#pragma unroll
  for (int i = 0; i < 4; ++i) {
    int c = tid + i * 256;
    int r = c >> 4, ko = c & 15;
    *reinterpret_cast<uint4*>(&ws[r][ko * 8]) =
        reinterpret_cast<const uint4*>(wo)[(size_t)r * 16 + ko];
  }
  __syncthreads();

  const int w = tid >> 6, lane = tid & 63;
  const int lr = lane & 15, lg = lane >> 4;
  f32x4 acc[4];
#pragma unroll
  for (int f = 0; f < 4; ++f) acc[f] = (f32x4){0.f, 0.f, 0.f, 0.f};

#pragma unroll
  for (int s = 0; s < 4; ++s) {
    bf16x8 a = *reinterpret_cast<const bf16x8*>(&xa[w * 16 + lr][s * 32 + lg * 8]);
#pragma unroll
    for (int f = 0; f < 4; ++f) {
      bf16x8 b = *reinterpret_cast<const bf16x8*>(&ws[f * 16 + lr][s * 32 + lg * 8]);
      acc[f] = __builtin_amdgcn_mfma_f32_16x16x32_bf16(a, b, acc[f], 0, 0, 0);
    }
  }
#pragma unroll
  for (int f = 0; f < 4; ++f) {
#pragma unroll
    for (int r = 0; r < 4; ++r) {
      int row = row0 + w * 16 + lg * 4 + r;
      if (row < n)
        out[(size_t)row * 64 + f * 16 + lr] = acc[f][r] + bias[f * 16 + lr];
    }
  }
}

// ---------------- fused segment softmax + aggregation + node update ----------------
// One wave per dst node. Per 8-edge chunk (branchless — padded slots have
// pe=0 and clamped address so all 8 gathers issue unconditionally):
//   phase1: lane=(el=lane>>3, hh=lane&7): p = exp(leaky(asd_s[col[e]][hh]+asd_d[node][hh]))
//   phase2: lane owns channels (2*lane, 2*lane+1); p via ds_bpermute, src via readlane.
__global__ __launch_bounds__(256) void k_aggregate(
    const unsigned int* __restrict__ ylin_pk, const unsigned int* __restrict__ xsp,
    const unsigned short* __restrict__ asd_s, const unsigned short* __restrict__ asd_d,
    const int* __restrict__ rowptr, const int* __restrict__ col,
    unsigned int* __restrict__ hout_pk, int n) {
  int node = (blockIdx.x * blockDim.x + threadIdx.x) >> 6;
  if (node >= n) return;
  const int lane = threadIdx.x & 63;
  const int el = lane >> 3;             // phase1 edge slot
  const int hh = lane & 7;              // phase1 head
  const int hb4 = (lane >> 3) << 2;     // phase2: h*4 bpermute byte base
  const int beg = rowptr[node], end = rowptr[node + 1];

  const float ad_hh = bf2f(asd_d[(size_t)node * 8 + hh]);

  float dsum = 0.f, acc0 = 0.f, acc1 = 0.f;
  for (int ebase = beg; ebase < end; ebase += 8) {
    int e1 = ebase + el;
    bool valid = e1 < end;
    int esafe = valid ? e1 : (end - 1);
    int srcp = __builtin_nontemporal_load(&col[esafe]);
    float sv = bf2f(asd_s[(size_t)srcp * 8 + hh]) + ad_hh;
    sv = fmaxf(sv, NEG_SLOPE * sv);
    float pe = valid ? __expf(sv) : 0.f;
#pragma unroll
    for (int q = 0; q < 8; ++q) {       // branchless: all 8 issue
      float pq = __uint_as_float(__builtin_amdgcn_ds_bpermute(
          q * 32 + hb4, __float_as_uint(pe)));
      int sq = __builtin_amdgcn_readlane(srcp, q * 8);
      unsigned int xv = xsp[(size_t)sq * 64 + lane];
      dsum += pq;
      acc0 += pq * pklo(xv);
      acc1 += pq * pkhi(xv);
    }
  }
  float inv = 1.f / (dsum + 1e-16f);
  unsigned int y = __builtin_nontemporal_load(&ylin_pk[(size_t)node * 64 + lane]);
  float l0 = pklo(y) + acc0 * inv;
  float l1 = pkhi(y) + acc1 * inv;
  l0 = l0 > 0.f ? l0 : __expf(l0) - 1.f;
  l1 = l1 > 0.f ? l1 : __expf(l1) - 1.f;
  hout_pk[(size_t)node * 64 + lane] =
      (unsigned int)f2bf(l0) | ((unsigned int)f2bf(l1) << 16);
}

// ---------------- launch ----------------
extern "C" void kernel_launch(void* const* d_in, const int* in_sizes, int n_in,
                              void* d_out, int out_size, void* d_ws, size_t ws_size,
                              hipStream_t stream) {
  const float* x      = (const float*)d_in[0];
  const int*   ei     = (const int*)d_in[1];
  const float* W_lin0 = (const float*)d_in[2];
  const float* b_lin0 = (const float*)d_in[3];
  const float* W_src0 = (const float*)d_in[4];
  const float* W_dst0 = (const float*)d_in[5];
  const float* att_s0 = (const float*)d_in[6];
  const float* att_d0 = (const float*)d_in[7];
  const float* b_cnv0 = (const float*)d_in[8];
  const float* W_lin1 = (const float*)d_in[9];
  const float* b_lin1 = (const float*)d_in[10];
  const float* W_src1 = (const float*)d_in[11];
  const float* W_dst1 = (const float*)d_in[12];
  const float* att_s1 = (const float*)d_in[13];
  const float* att_d1 = (const float*)d_in[14];
  const float* b_cnv1 = (const float*)d_in[15];
  const float* W_out  = (const float*)d_in[16];
  const float* b_out  = (const float*)d_in[17];
  float* out = (float*)d_out;

  const int N = in_sizes[0] / 128;
  const int E = in_sizes[1] / 2;
  const int NB = (N + 1023) / 1024;
  const int NTILES = (N + 63) / 64;

  char* p = (char*)d_ws;
  unsigned int* ylin    = (unsigned int*)p;   p += (size_t)N * 64 * 4;
  unsigned short* xsb   = (unsigned short*)p; p += (size_t)N * 128 * 2;
  unsigned short* hb    = (unsigned short*)p; p += (size_t)N * 128 * 2;
  unsigned short* asd_s = (unsigned short*)p; p += (size_t)N * 8 * 2;
  unsigned short* asd_d = (unsigned short*)p; p += (size_t)N * 8 * 2;
  unsigned short* wt0   = (unsigned short*)p; p += (size_t)272 * 128 * 2;
  unsigned short* wt1   = (unsigned short*)p; p += (size_t)272 * 128 * 2;
  unsigned short* wot   = (unsigned short*)p; p += (size_t)64 * 128 * 2;
  int* rowptr = (int*)p;                      p += (size_t)(N + 4) * 4;
  int* cursor = (int*)p;                      p += (size_t)N * 4;
  int* deg    = (int*)p;                      p += (size_t)N * 4;
  int* lex    = (int*)p;                      p += (size_t)N * 4;
  int* bsum   = (int*)p;                      p += (size_t)256 * 4;
  int* col    = (int*)p;                      p += (size_t)E * 4;

  dim3 b256(256);

  // CSR by dst (shared by both layers)
  k_zero_i32<<<(N + 255) / 256, b256, 0, stream>>>(deg, N);
  k_degree<<<(E + 255) / 256, b256, 0, stream>>>(ei, deg, E);
  k_scan_local<<<NB, b256, 0, stream>>>(deg, lex, bsum, N);
  k_scan_bsum<<<1, b256, 0, stream>>>(bsum, NB);
  k_scan_add<<<(N + 256) / 256, b256, 0, stream>>>(lex, bsum, rowptr, cursor, N, E);
  k_scatter<<<(E + 255) / 256, b256, 0, stream>>>(ei, cursor, col, E);

  // all weight packs in one launch
  k_pack_all<<<(2 * 272 * 128 + 64 * 128 + 255) / 256, b256, 0, stream>>>(
      W_lin0, W_src0, W_dst0, att_s0, att_d0,
      W_lin1, W_src1, W_dst1, att_s1, att_d1,
      W_out, wt0, wt1, wot);

  for (int layer = 0; layer < 2; ++layer) {
    const float* bl = layer ? b_lin1 : b_lin0;
    const float* bc = layer ? b_cnv1 : b_cnv0;
    const unsigned short* wt = layer ? wt1 : wt0;

    if (layer == 0)
      k_gemm_fused<float><<<256, 512, 0, stream>>>(x, wt, bl, bc, ylin, xsb,
                                                   asd_s, asd_d, N, NTILES);
    else
      k_gemm_fused<unsigned short><<<256, 512, 0, stream>>>(hb, wt, bl, bc, ylin, xsb,
                                                            asd_s, asd_d, N, NTILES);
    k_aggregate<<<(N + 3) / 4, b256, 0, stream>>>(
        ylin, (const unsigned int*)xsb, asd_s, asd_d, rowptr, col,
        (unsigned int*)hb, N);
  }
  k_gemm_out<<<(N + 63) / 64, b256, 0, stream>>>(hb, wot, b_out, out, N);
}

// Round 10
// 199.379 us; speedup vs baseline: 1.2440x; 1.1167x over previous
//
#include <hip/hip_runtime.h>
#include <cstdint>
#include <cstddef>

#define NEG_SLOPE 0.2f

typedef __bf16 bf16x8 __attribute__((ext_vector_type(8)));
typedef float f32x4 __attribute__((ext_vector_type(4)));

static __device__ __forceinline__ unsigned short f2bf(float f) {
  unsigned int u = __float_as_uint(f);
  unsigned int r = (u + 0x7FFFu + ((u >> 16) & 1u)) >> 16;
  return (unsigned short)r;
}
static __device__ __forceinline__ float bf2f(unsigned short u) {
  return __uint_as_float(((unsigned int)u) << 16);
}
static __device__ __forceinline__ float pklo(unsigned int x) {
  return __uint_as_float(x << 16);
}
static __device__ __forceinline__ float pkhi(unsigned int x) {
  return __uint_as_float(x & 0xffff0000u);
}

// ---------------- CSR build ----------------
__global__ void k_zero_i32(int* __restrict__ p, int n) {
  int i = blockIdx.x * 256 + threadIdx.x;
  if (i < n) p[i] = 0;
}

__global__ void k_degree(const int* __restrict__ ei, int* __restrict__ deg, int E) {
  int e = blockIdx.x * 256 + threadIdx.x;
  if (e < E) atomicAdd(&deg[ei[E + e]], 1);  // ei[E+e] = dst
}

__global__ __launch_bounds__(256) void k_scan_local(const int* __restrict__ deg,
                                                    int* __restrict__ lex,
                                                    int* __restrict__ bsum, int n) {
  __shared__ int ts[256];
  const int t = threadIdx.x;
  const int base = blockIdx.x * 1024 + t * 4;
  int4 d = {0, 0, 0, 0};
  if (base + 3 < n) d = *reinterpret_cast<const int4*>(&deg[base]);
  else {
    if (base + 0 < n) d.x = deg[base + 0];
    if (base + 1 < n) d.y = deg[base + 1];
    if (base + 2 < n) d.z = deg[base + 2];
  }
  int s = d.x + d.y + d.z + d.w;
  ts[t] = s;
  __syncthreads();
  for (int off = 1; off < 256; off <<= 1) {
    int y = (t >= off) ? ts[t - off] : 0;
    __syncthreads();
    ts[t] += y;
    __syncthreads();
  }
  int pre = ts[t] - s;
  int4 o;
  o.x = pre; o.y = pre + d.x; o.z = pre + d.x + d.y; o.w = pre + d.x + d.y + d.z;
  if (base + 3 < n) *reinterpret_cast<int4*>(&lex[base]) = o;
  else {
    if (base + 0 < n) lex[base + 0] = o.x;
    if (base + 1 < n) lex[base + 1] = o.y;
    if (base + 2 < n) lex[base + 2] = o.z;
  }
  if (t == 255) bsum[blockIdx.x] = ts[255];
}

__global__ __launch_bounds__(256) void k_scan_bsum(int* __restrict__ bsum, int nb) {
  __shared__ int ts[256];
  const int t = threadIdx.x;
  int v = (t < nb) ? bsum[t] : 0;
  ts[t] = v;
  __syncthreads();
  for (int off = 1; off < 256; off <<= 1) {
    int y = (t >= off) ? ts[t - off] : 0;
    __syncthreads();
    ts[t] += y;
    __syncthreads();
  }
  if (t < nb) bsum[t] = ts[t] - v;
}

__global__ void k_scan_add(const int* __restrict__ lex, const int* __restrict__ bsum,
                           int* __restrict__ rowptr, int* __restrict__ cursor,
                           int n, int E) {
  int i = blockIdx.x * 256 + threadIdx.x;
  if (i < n) {
    int v = lex[i] + bsum[i >> 10];
    rowptr[i] = v;
    cursor[i] = v;
  }
  if (i == n) rowptr[n] = E;
}

__global__ void k_scatter(const int* __restrict__ ei, int* __restrict__ cursor,
                          int* __restrict__ col, int E) {
  int e = blockIdx.x * 256 + threadIdx.x;
  if (e >= E) return;
  int d = ei[E + e];
  int pos = atomicAdd(&cursor[d], 1);
  col[pos] = ei[e];
}

// ---------------- weight prep (all layers in one launch) ----------------
static __device__ __forceinline__ unsigned short pack_wt_elem(
    const float* __restrict__ Wl, const float* __restrict__ Ws,
    const float* __restrict__ Wd, const float* __restrict__ as_,
    const float* __restrict__ ad_, int t) {
  int j = t >> 7, k = t & 127;
  float val;
  if (j < 128) val = Wl[k * 128 + j];
  else if (j < 256) val = Ws[k * 128 + (j - 128)];
  else {
    int jj = j - 256;
    int h = jj & 7;
    const float* W = (jj < 8) ? Ws : Wd;
    const float* a = (jj < 8) ? as_ : ad_;
    float s = 0.f;
#pragma unroll
    for (int c = 0; c < 16; ++c) s += W[k * 128 + h * 16 + c] * a[h * 16 + c];
    val = s;
  }
  return f2bf(val);
}

__global__ void k_pack_all(
    const float* __restrict__ Wl0, const float* __restrict__ Ws0, const float* __restrict__ Wd0,
    const float* __restrict__ as0, const float* __restrict__ ad0,
    const float* __restrict__ Wl1, const float* __restrict__ Ws1, const float* __restrict__ Wd1,
    const float* __restrict__ as1, const float* __restrict__ ad1,
    const float* __restrict__ Wo,
    unsigned short* __restrict__ wt0, unsigned short* __restrict__ wt1,
    unsigned short* __restrict__ wot) {
  const int SZ = 272 * 128;
  int t = blockIdx.x * 256 + threadIdx.x;
  if (t < SZ) {
    wt0[t] = pack_wt_elem(Wl0, Ws0, Wd0, as0, ad0, t);
  } else if (t < 2 * SZ) {
    wt1[t - SZ] = pack_wt_elem(Wl1, Ws1, Wd1, as1, ad1, t - SZ);
  } else if (t < 2 * SZ + 64 * 128) {
    int u = t - 2 * SZ;
    int nn = u >> 7, k = u & 127;
    wot[u] = f2bf(Wo[k * 64 + nn]);
  }
}

// ---------------- fused MFMA GEMM (non-persistent, B in registers) ----------------
// 32-row tile, 256 threads = 4 waves = 4 f-slices (wave 3 also owns asd frag).
// Outputs: ylin_pk[N][64] uint (bf16 pairs, biases folded), xsb[N][128] bf16,
// asd_s/asd_d[N][8] bf16.
template <typename TIN>
__global__ __launch_bounds__(256, 3) void k_gemm_fused(
    const TIN* __restrict__ X, const unsigned short* __restrict__ wt,
    const float* __restrict__ bl, const float* __restrict__ bc,
    unsigned int* __restrict__ ylin_pk, unsigned short* __restrict__ xsb,
    unsigned short* __restrict__ asd_s, unsigned short* __restrict__ asd_d,
    int n) {
  __shared__ __align__(16) unsigned short xa[32][136];
  const int tid = threadIdx.x;
  const int wave = tid >> 6, lane = tid & 63;
  const int lr = lane & 15, lg = lane >> 4;
  const int row0 = blockIdx.x * 32;
  const int f0 = wave * 4;
  const bool w3 = (wave == 3);

  // B fragments from global (L2-hot, identical across blocks)
  bf16x8 bfr[4][4];
#pragma unroll
  for (int ff = 0; ff < 4; ++ff)
#pragma unroll
    for (int s = 0; s < 4; ++s)
      bfr[ff][s] = *reinterpret_cast<const bf16x8*>(
          &wt[(size_t)((f0 + ff) * 16 + lr) * 128 + s * 32 + lg * 8]);
  bf16x8 bfr4[4];
  if (w3) {
#pragma unroll
    for (int s = 0; s < 4; ++s)
      bfr4[s] = *reinterpret_cast<const bf16x8*>(
          &wt[(size_t)(256 + lr) * 128 + s * 32 + lg * 8]);
  }

  // stage X tile (32 rows x 128) into LDS as bf16
  if constexpr (sizeof(TIN) == 4) {
#pragma unroll
    for (int i = 0; i < 4; ++i) {
      int c = tid + i * 256;          // 1024 float4 chunks
      int r = c >> 5, kq = c & 31;
      float4 v = make_float4(0.f, 0.f, 0.f, 0.f);
      if (row0 + r < n)
        v = reinterpret_cast<const float4*>(X)[(size_t)(row0 + r) * 32 + kq];
      ushort4 o;
      o.x = f2bf(v.x); o.y = f2bf(v.y); o.z = f2bf(v.z); o.w = f2bf(v.w);
      *reinterpret_cast<ushort4*>(&xa[r][kq * 4]) = o;
    }
  } else {
#pragma unroll
    for (int i = 0; i < 2; ++i) {
      int c = tid + i * 256;          // 512 uint4 chunks
      int r = c >> 4, ko = c & 15;
      uint4 v = {0u, 0u, 0u, 0u};
      if (row0 + r < n)
        v = reinterpret_cast<const uint4*>(X)[(size_t)(row0 + r) * 16 + ko];
      *reinterpret_cast<uint4*>(&xa[r][ko * 8]) = v;
    }
  }
  __syncthreads();

  f32x4 acc[2][4];
  f32x4 acc4[2];
#pragma unroll
  for (int g = 0; g < 2; ++g) {
    acc4[g] = (f32x4){0.f, 0.f, 0.f, 0.f};
#pragma unroll
    for (int ff = 0; ff < 4; ++ff) acc[g][ff] = (f32x4){0.f, 0.f, 0.f, 0.f};
  }

#pragma unroll
  for (int s = 0; s < 4; ++s) {
    bf16x8 a0 = *reinterpret_cast<const bf16x8*>(&xa[lr][s * 32 + lg * 8]);
    bf16x8 a1 = *reinterpret_cast<const bf16x8*>(&xa[16 + lr][s * 32 + lg * 8]);
#pragma unroll
    for (int ff = 0; ff < 4; ++ff) {
      acc[0][ff] = __builtin_amdgcn_mfma_f32_16x16x32_bf16(a0, bfr[ff][s], acc[0][ff], 0, 0, 0);
      acc[1][ff] = __builtin_amdgcn_mfma_f32_16x16x32_bf16(a1, bfr[ff][s], acc[1][ff], 0, 0, 0);
    }
    if (w3) {
      acc4[0] = __builtin_amdgcn_mfma_f32_16x16x32_bf16(a0, bfr4[s], acc4[0], 0, 0, 0);
      acc4[1] = __builtin_amdgcn_mfma_f32_16x16x32_bf16(a1, bfr4[s], acc4[1], 0, 0, 0);
    }
  }

  if (f0 < 8) {   // ylin region (waves 0-1), packed bf16 pairs, biases folded
#pragma unroll
    for (int g = 0; g < 2; ++g)
#pragma unroll
      for (int ff = 0; ff < 4; ++ff) {
        int j = (f0 + ff) * 16 + lr;
        float blc = bl[j] + bc[j];
#pragma unroll
        for (int r = 0; r < 4; ++r) {
          int row = row0 + g * 16 + lg * 4 + r;
          float vb = acc[g][ff][r] + blc;
          float v2 = __shfl(vb, lane ^ 1);
          if (row < n && (lr & 1) == 0)
            ylin_pk[(size_t)row * 64 + (j >> 1)] =
                (unsigned int)f2bf(vb) | ((unsigned int)f2bf(v2) << 16);
        }
      }
  } else {        // xsb region (waves 2-3)
#pragma unroll
    for (int g = 0; g < 2; ++g)
#pragma unroll
      for (int ff = 0; ff < 4; ++ff) {
        int j = (f0 - 8 + ff) * 16 + lr;
#pragma unroll
        for (int r = 0; r < 4; ++r) {
          int row = row0 + g * 16 + lg * 4 + r;
          if (row < n) xsb[(size_t)row * 128 + j] = f2bf(acc[g][ff][r]);
        }
      }
    if (w3) {
#pragma unroll
      for (int g = 0; g < 2; ++g)
#pragma unroll
        for (int r = 0; r < 4; ++r) {
          int row = row0 + g * 16 + lg * 4 + r;
          if (row < n) {
            unsigned short v = f2bf(acc4[g][r]);
            if (lr < 8) asd_s[(size_t)row * 8 + lr] = v;
            else        asd_d[(size_t)row * 8 + (lr - 8)] = v;
          }
        }
    }
  }
}

// ---------------- final MFMA GEMM: out[N,64] = h@W_out + b (h bf16) ----------------
__global__ __launch_bounds__(256) void k_gemm_out(
    const unsigned short* __restrict__ X, const unsigned short* __restrict__ wo,
    const float* __restrict__ bias, float* __restrict__ out, int n) {
  __shared__ __align__(16) unsigned short xa[64][136];
  __shared__ __align__(16) unsigned short ws[64][136];
  const int tid = threadIdx.x;
  const int row0 = blockIdx.x * 64;

#pragma unroll
  for (int i = 0; i < 4; ++i) {
    int c = tid + i * 256;
    int r = c >> 4, ko = c & 15;
    uint4 v = {0u, 0u, 0u, 0u};
    if (row0 + r < n)
      v = reinterpret_cast<const uint4*>(X)[(size_t)(row0 + r) * 16 + ko];
    *reinterpret_cast<uint4*>(&xa[r][ko * 8]) = v;
  }
#pragma unroll
  for (int i = 0; i < 4; ++i) {
    int c = tid + i * 256;
    int r = c >> 4, ko = c & 15;
    *reinterpret_cast<uint4*>(&ws[r][ko * 8]) =
        reinterpret_cast<const uint4*>(wo)[(size_t)r * 16 + ko];
  }
  __syncthreads();

  const int w = tid >> 6, lane = tid & 63;
  const int lr = lane & 15, lg = lane >> 4;
  f32x4 acc[4];
#pragma unroll
  for (int f = 0; f < 4; ++f) acc[f] = (f32x4){0.f, 0.f, 0.f, 0.f};

#pragma unroll
  for (int s = 0; s < 4; ++s) {
    bf16x8 a = *reinterpret_cast<const bf16x8*>(&xa[w * 16 + lr][s * 32 + lg * 8]);
#pragma unroll
    for (int f = 0; f < 4; ++f) {
      bf16x8 b = *reinterpret_cast<const bf16x8*>(&ws[f * 16 + lr][s * 32 + lg * 8]);
      acc[f] = __builtin_amdgcn_mfma_f32_16x16x32_bf16(a, b, acc[f], 0, 0, 0);
    }
  }
#pragma unroll
  for (int f = 0; f < 4; ++f) {
#pragma unroll
    for (int r = 0; r < 4; ++r) {
      int row = row0 + w * 16 + lg * 4 + r;
      if (row < n)
        out[(size_t)row * 64 + f * 16 + lr] = acc[f][r] + bias[f * 16 + lr];
    }
  }
}

// ---------------- fused segment softmax + aggregation + node update ----------------
// One wave per dst node. Per 8-edge chunk (branchless — padded slots have
// pe=0 and clamped address so all 8 gathers issue unconditionally):
//   phase1: lane=(el=lane>>3, hh=lane&7): p = exp(leaky(asd_s[col[e]][hh]+asd_d[node][hh]))
//   phase2: lane owns channels (2*lane, 2*lane+1); p via ds_bpermute, src via readlane.
__global__ __launch_bounds__(256) void k_aggregate(
    const unsigned int* __restrict__ ylin_pk, const unsigned int* __restrict__ xsp,
    const unsigned short* __restrict__ asd_s, const unsigned short* __restrict__ asd_d,
    const int* __restrict__ rowptr, const int* __restrict__ col,
    unsigned int* __restrict__ hout_pk, int n) {
  int node = (blockIdx.x * blockDim.x + threadIdx.x) >> 6;
  if (node >= n) return;
  const int lane = threadIdx.x & 63;
  const int el = lane >> 3;             // phase1 edge slot
  const int hh = lane & 7;              // phase1 head
  const int hb4 = (lane >> 3) << 2;     // phase2: h*4 bpermute byte base
  const int beg = rowptr[node], end = rowptr[node + 1];

  const float ad_hh = bf2f(asd_d[(size_t)node * 8 + hh]);

  float dsum = 0.f, acc0 = 0.f, acc1 = 0.f;
  for (int ebase = beg; ebase < end; ebase += 8) {
    int e1 = ebase + el;
    bool valid = e1 < end;
    int esafe = valid ? e1 : (end - 1);
    int srcp = __builtin_nontemporal_load(&col[esafe]);
    float sv = bf2f(asd_s[(size_t)srcp * 8 + hh]) + ad_hh;
    sv = fmaxf(sv, NEG_SLOPE * sv);
    float pe = valid ? __expf(sv) : 0.f;
#pragma unroll
    for (int q = 0; q < 8; ++q) {       // branchless: all 8 issue
      float pq = __uint_as_float(__builtin_amdgcn_ds_bpermute(
          q * 32 + hb4, __float_as_uint(pe)));
      int sq = __builtin_amdgcn_readlane(srcp, q * 8);
      unsigned int xv = xsp[(size_t)sq * 64 + lane];
      dsum += pq;
      acc0 += pq * pklo(xv);
      acc1 += pq * pkhi(xv);
    }
  }
  float inv = 1.f / (dsum + 1e-16f);
  unsigned int y = __builtin_nontemporal_load(&ylin_pk[(size_t)node * 64 + lane]);
  float l0 = pklo(y) + acc0 * inv;
  float l1 = pkhi(y) + acc1 * inv;
  l0 = l0 > 0.f ? l0 : __expf(l0) - 1.f;
  l1 = l1 > 0.f ? l1 : __expf(l1) - 1.f;
  hout_pk[(size_t)node * 64 + lane] =
      (unsigned int)f2bf(l0) | ((unsigned int)f2bf(l1) << 16);
}

// ---------------- launch ----------------
extern "C" void kernel_launch(void* const* d_in, const int* in_sizes, int n_in,
                              void* d_out, int out_size, void* d_ws, size_t ws_size,
                              hipStream_t stream) {
  const float* x      = (const float*)d_in[0];
  const int*   ei     = (const int*)d_in[1];
  const float* W_lin0 = (const float*)d_in[2];
  const float* b_lin0 = (const float*)d_in[3];
  const float* W_src0 = (const float*)d_in[4];
  const float* W_dst0 = (const float*)d_in[5];
  const float* att_s0 = (const float*)d_in[6];
  const float* att_d0 = (const float*)d_in[7];
  const float* b_cnv0 = (const float*)d_in[8];
  const float* W_lin1 = (const float*)d_in[9];
  const float* b_lin1 = (const float*)d_in[10];
  const float* W_src1 = (const float*)d_in[11];
  const float* W_dst1 = (const float*)d_in[12];
  const float* att_s1 = (const float*)d_in[13];
  const float* att_d1 = (const float*)d_in[14];
  const float* b_cnv1 = (const float*)d_in[15];
  const float* W_out  = (const float*)d_in[16];
  const float* b_out  = (const float*)d_in[17];
  float* out = (float*)d_out;

  const int N = in_sizes[0] / 128;
  const int E = in_sizes[1] / 2;
  const int NB = (N + 1023) / 1024;
  const int MB32 = (N + 31) / 32;

  char* p = (char*)d_ws;
  unsigned int* ylin    = (unsigned int*)p;   p += (size_t)N * 64 * 4;
  unsigned short* xsb   = (unsigned short*)p; p += (size_t)N * 128 * 2;
  unsigned short* hb    = (unsigned short*)p; p += (size_t)N * 128 * 2;
  unsigned short* asd_s = (unsigned short*)p; p += (size_t)N * 8 * 2;
  unsigned short* asd_d = (unsigned short*)p; p += (size_t)N * 8 * 2;
  unsigned short* wt0   = (unsigned short*)p; p += (size_t)272 * 128 * 2;
  unsigned short* wt1   = (unsigned short*)p; p += (size_t)272 * 128 * 2;
  unsigned short* wot   = (unsigned short*)p; p += (size_t)64 * 128 * 2;
  int* rowptr = (int*)p;                      p += (size_t)(N + 4) * 4;
  int* cursor = (int*)p;                      p += (size_t)N * 4;
  int* deg    = (int*)p;                      p += (size_t)N * 4;
  int* lex    = (int*)p;                      p += (size_t)N * 4;
  int* bsum   = (int*)p;                      p += (size_t)256 * 4;
  int* col    = (int*)p;                      p += (size_t)E * 4;

  dim3 b256(256);

  // CSR by dst (shared by both layers)
  k_zero_i32<<<(N + 255) / 256, b256, 0, stream>>>(deg, N);
  k_degree<<<(E + 255) / 256, b256, 0, stream>>>(ei, deg, E);
  k_scan_local<<<NB, b256, 0, stream>>>(deg, lex, bsum, N);
  k_scan_bsum<<<1, b256, 0, stream>>>(bsum, NB);
  k_scan_add<<<(N + 256) / 256, b256, 0, stream>>>(lex, bsum, rowptr, cursor, N, E);
  k_scatter<<<(E + 255) / 256, b256, 0, stream>>>(ei, cursor, col, E);

  // all weight packs in one launch
  k_pack_all<<<(2 * 272 * 128 + 64 * 128 + 255) / 256, b256, 0, stream>>>(
      W_lin0, W_src0, W_dst0, att_s0, att_d0,
      W_lin1, W_src1, W_dst1, att_s1, att_d1,
      W_out, wt0, wt1, wot);

  for (int layer = 0; layer < 2; ++layer) {
    const float* bl = layer ? b_lin1 : b_lin0;
    const float* bc = layer ? b_cnv1 : b_cnv0;
    const unsigned short* wt = layer ? wt1 : wt0;

    if (layer == 0)
      k_gemm_fused<float><<<MB32, b256, 0, stream>>>(x, wt, bl, bc, ylin, xsb,
                                                     asd_s, asd_d, N);
    else
      k_gemm_fused<unsigned short><<<MB32, b256, 0, stream>>>(hb, wt, bl, bc, ylin, xsb,
                                                              asd_s, asd_d, N);
    k_aggregate<<<(N + 3) / 4, b256, 0, stream>>>(
        ylin, (const unsigned int*)xsb, asd_s, asd_d, rowptr, col,
        (unsigned int*)hb, N);
  }
  k_gemm_out<<<(N + 63) / 64, b256, 0, stream>>>(hb, wot, b_out, out, N);
}